// Round 3
// baseline (847.184 us; speedup 1.0000x reference)
//
#include <hip/hip_runtime.h>
#include <cstdint>

#define SEQ   4096
#define DM    768
#define NH    12
#define HD    64
#define KD    768

typedef float  f32x4  __attribute__((ext_vector_type(4)));
typedef short  bf16x8 __attribute__((ext_vector_type(8)));

typedef __attribute__((address_space(1))) const unsigned int gu32;
typedef __attribute__((address_space(3))) unsigned int lu32;

__device__ __forceinline__ unsigned short f2b(float f) {
  unsigned int u = __builtin_bit_cast(unsigned int, f);
  u += 0x7fffu + ((u >> 16) & 1u);
  return (unsigned short)(u >> 16);
}
__device__ __forceinline__ float b2f(unsigned short s) {
  return __builtin_bit_cast(float, ((unsigned int)s) << 16);
}

__device__ __forceinline__ void gload_lds16(const void* g, void* l) {
  gu32* gp = reinterpret_cast<gu32*>(reinterpret_cast<uintptr_t>(g));
  lu32* lp = reinterpret_cast<lu32*>(reinterpret_cast<uintptr_t>(l));
  __builtin_amdgcn_global_load_lds(gp, lp, 16, 0, 0);
}

// ---------------- pack/convert: f32 -> bf16 ----------------
__global__ void convert_all(const float* __restrict__ x,
                            const float* __restrict__ wq,
                            const float* __restrict__ wk,
                            const float* __restrict__ wv,
                            const float* __restrict__ wo,
                            unsigned short* __restrict__ xb,
                            unsigned short* __restrict__ wqkv,
                            unsigned short* __restrict__ wob)
{
  const int XN = SEQ * DM;
  const int WN = DM * DM;
  const int total4 = (XN + 4 * WN) >> 2;
  for (int i = blockIdx.x * blockDim.x + threadIdx.x; i < total4;
       i += gridDim.x * blockDim.x) {
    const int base = i << 2;
    const float* src;
    unsigned short* dst;
    if (base < XN)                 { src = x  + base;               dst = xb   + base; }
    else if (base < XN + WN)       { src = wq + (base - XN);        dst = wqkv + (base - XN); }
    else if (base < XN + 2 * WN)   { src = wk + (base - XN - WN);   dst = wqkv + (base - XN); }
    else if (base < XN + 3 * WN)   { src = wv + (base - XN - 2*WN); dst = wqkv + (base - XN); }
    else                           { src = wo + (base - XN - 3*WN); dst = wob  + (base - XN - 3*WN); }
    const float4 v = *(const float4*)src;
    *(ushort4*)dst = make_ushort4(f2b(v.x), f2b(v.y), f2b(v.z), f2b(v.w));
  }
}

// ---------------- GEMM C = A[M,K] * B[N,K]^T, m97-style ----------------
// EPI 0: QKV epilogue (q scaled by 0.125; q,k,v all row-major [h][s][dk])
// EPI 1: out epilogue (f32 + bo)
template<int EPI>
__global__ __launch_bounds__(256, 2)
void gemm_bt(const unsigned short* __restrict__ A,
             const unsigned short* __restrict__ B,
             unsigned short* __restrict__ qb,
             unsigned short* __restrict__ kb,
             unsigned short* __restrict__ vb,
             const float* __restrict__ bq,
             const float* __restrict__ bk,
             const float* __restrict__ bv,
             const float* __restrict__ bo,
             float* __restrict__ outf)
{
  __shared__ __align__(16) unsigned short As[128 * 32];
  __shared__ __align__(16) unsigned short Bs[128 * 32];
  const int t  = threadIdx.x;
  const int w  = t >> 6;
  const int l  = t & 63;
  const int m0 = blockIdx.y * 128;
  const int n0 = blockIdx.x * 128;
  const int wr = (w >> 1) * 64;
  const int wc = (w & 1) * 64;
  const int lr = l & 15;
  const int lk = (l >> 4) * 8;

  const int row1 = t >> 2;
  const int row2 = row1 + 64;
  const int seg  = t & 3;

  f32x4 acc[4][4];
#pragma unroll
  for (int i = 0; i < 4; i++)
#pragma unroll
    for (int j = 0; j < 4; j++) acc[i][j] = (f32x4){0.f, 0.f, 0.f, 0.f};

  char* ldsA0 = (char*)As + (size_t)(w * 64) * 16;
  char* ldsA1 = (char*)As + (size_t)(w * 64 + 256) * 16;
  char* ldsB0 = (char*)Bs + (size_t)(w * 64) * 16;
  char* ldsB1 = (char*)Bs + (size_t)(w * 64 + 256) * 16;

  for (int k0 = 0; k0 < KD; k0 += 32) {
    gload_lds16(A + (size_t)(m0 + row1) * KD + k0 + seg * 8, ldsA0);
    gload_lds16(A + (size_t)(m0 + row2) * KD + k0 + seg * 8, ldsA1);
    gload_lds16(B + (size_t)(n0 + row1) * KD + k0 + seg * 8, ldsB0);
    gload_lds16(B + (size_t)(n0 + row2) * KD + k0 + seg * 8, ldsB1);
    __syncthreads();
    bf16x8 af[4], bfv[4];
#pragma unroll
    for (int fi = 0; fi < 4; fi++)
      af[fi] = *(const bf16x8*)(As + (wr + fi * 16 + lr) * 32 + lk);
#pragma unroll
    for (int fj = 0; fj < 4; fj++)
      bfv[fj] = *(const bf16x8*)(Bs + (wc + fj * 16 + lr) * 32 + lk);
#pragma unroll
    for (int fi = 0; fi < 4; fi++)
#pragma unroll
      for (int fj = 0; fj < 4; fj++)
        acc[fi][fj] = __builtin_amdgcn_mfma_f32_16x16x32_bf16(af[fi], bfv[fj], acc[fi][fj], 0, 0, 0);
    __syncthreads();
  }

#pragma unroll
  for (int fi = 0; fi < 4; fi++) {
    const int mbase = m0 + wr + fi * 16 + (l >> 4) * 4;
#pragma unroll
    for (int fj = 0; fj < 4; fj++) {
      const int n = n0 + wc + fj * 16 + lr;
      if (EPI == 1) {
        const float bb = bo[n];
#pragma unroll
        for (int r = 0; r < 4; r++)
          outf[(size_t)(mbase + r) * DM + n] = acc[fi][fj][r] + bb;
      } else if (n < DM) {                       // Q (scaled by 1/8)
        const int hh = n >> 6, dk = n & 63;
        const float bb = bq[n];
#pragma unroll
        for (int r = 0; r < 4; r++)
          qb[((size_t)hh * SEQ + mbase + r) * HD + dk] = f2b((acc[fi][fj][r] + bb) * 0.125f);
      } else if (n < 2 * DM) {                   // K row-major [h][s][dk]
        const int n2 = n - DM, hh = n2 >> 6, dk = n2 & 63;
        const float bb = bk[n2];
#pragma unroll
        for (int r = 0; r < 4; r++)
          kb[((size_t)hh * SEQ + mbase + r) * HD + dk] = f2b(acc[fi][fj][r] + bb);
      } else {                                   // V row-major [h][s][dk]
        const int n3 = n - 2 * DM, hh = n3 >> 6, dk = n3 & 63;
        const float bb = bv[n3];
#pragma unroll
        for (int r = 0; r < 4; r++)
          vb[((size_t)hh * SEQ + mbase + r) * HD + dk] = f2b(acc[fi][fj][r] + bb);
      }
    }
  }
}

// ---------------- NAIVE attention probe: one wave per (head, query row) ------
// Pure scalar f32 math, shfl-only communication, no MFMA / no LDS / no layout
// assumptions. mask: valid(qi,j) = (qi==0) || (j==0) || |qi-j| <= 256.
__global__ __launch_bounds__(256)
void attn_naive(const unsigned short* __restrict__ qb,
                const unsigned short* __restrict__ kb,
                const unsigned short* __restrict__ vb,
                unsigned short* __restrict__ ctx)
{
  const int h    = blockIdx.y;
  const int w    = threadIdx.x >> 6;
  const int lane = threadIdx.x & 63;
  const int qi   = blockIdx.x * 4 + w;

  const unsigned short* Qh = qb + (size_t)h * SEQ * HD;
  const unsigned short* Kh = kb + (size_t)h * SEQ * HD;
  const unsigned short* Vh = vb + (size_t)h * SEQ * HD;

  const float qv = b2f(Qh[(size_t)qi * HD + lane]);   // lane d holds q_d (pre-scaled)

  int cbeg, cend;
  if (qi == 0) { cbeg = 0; cend = (SEQ / 64) - 1; }
  else {
    int lo = qi - 256; if (lo < 0) lo = 0;
    int hi = qi + 257; if (hi > SEQ) hi = SEQ;
    cbeg = lo >> 6; cend = (hi - 1) >> 6;
  }
  const int cfirst = (cbeg > 0) ? (cbeg - 1) : cbeg;

  float o = 0.f, m = -1e30f, lsum = 0.f;

  for (int cc = cfirst; cc <= cend; cc++) {
    const int c  = (cc < cbeg) ? 0 : cc;
    const int j  = c * 64 + lane;                 // this lane's key

    // s_j = q . k_j  (full f32, q broadcast via shfl)
    float s = 0.f;
    const unsigned short* Kp = Kh + (size_t)j * HD;
    for (int d0 = 0; d0 < HD; d0 += 8) {
      const bf16x8 kv = *(const bf16x8*)(Kp + d0);
#pragma unroll
      for (int e = 0; e < 8; e++)
        s += __shfl(qv, d0 + e) * b2f((unsigned short)kv[e]);
    }
    const bool valid = (qi == 0) || (j == 0) ||
                       ((j - qi) <= 256 && (qi - j) <= 256);
    s = valid ? s : -1e30f;

    // wave-wide online softmax update
    float mx = s;
    for (int d = 1; d < 64; d <<= 1) mx = fmaxf(mx, __shfl_xor(mx, d));
    const float mnew  = fmaxf(m, mx);
    const float esc   = __expf(m - mnew);
    const float p     = __expf(s - mnew);
    float psum = p;
    for (int d = 1; d < 64; d <<= 1) psum += __shfl_xor(psum, d);
    lsum = lsum * esc + psum;
    o   *= esc;

    // o_d += sum_jj p_jj * V[c*64+jj][d]   (lane d owns output dim d)
    for (int jj = 0; jj < 64; jj++) {
      const float pj = __shfl(p, jj);
      o += pj * b2f(Vh[(size_t)(c * 64 + jj) * HD + lane]);
    }
    m = mnew;
  }

  ctx[(size_t)qi * DM + h * HD + lane] = f2b(o / lsum);
}

// ---------------- launch ----------------
extern "C" void kernel_launch(void* const* d_in, const int* in_sizes, int n_in,
                              void* d_out, int out_size, void* d_ws, size_t ws_size,
                              hipStream_t stream)
{
  (void)in_sizes; (void)n_in; (void)out_size; (void)ws_size;
  const float* x  = (const float*)d_in[0];
  const float* Wq = (const float*)d_in[1];
  const float* bq = (const float*)d_in[2];
  const float* Wk = (const float*)d_in[3];
  const float* bk = (const float*)d_in[4];
  const float* Wv = (const float*)d_in[5];
  const float* bv = (const float*)d_in[6];
  const float* Wo = (const float*)d_in[7];
  const float* bo = (const float*)d_in[8];
  float* out = (float*)d_out;

  char* ws = (char*)d_ws;
  unsigned short* xb   = (unsigned short*)(ws + 0);         // 4096x768 bf16 (dead after gemm<0>)
  unsigned short* wqkv = (unsigned short*)(ws + 6291456);   // 2304x768 bf16
  unsigned short* wob  = (unsigned short*)(ws + 9830400);   // 768x768 bf16
  unsigned short* qbuf = (unsigned short*)(ws + 11010048);  // [12][4096][64]
  unsigned short* kbuf = (unsigned short*)(ws + 17301504);  // [12][4096][64]
  unsigned short* vbuf = (unsigned short*)(ws + 23592960);  // [12][4096][64]
  unsigned short* ctx  = (unsigned short*)(ws + 0);         // aliases xb (safe: xb dead)

  convert_all<<<dim3(1024), dim3(256), 0, stream>>>(x, Wq, Wk, Wv, Wo, xb, wqkv, wob);
  gemm_bt<0><<<dim3(18, 32), dim3(256), 0, stream>>>(xb, wqkv, qbuf, kbuf, vbuf,
                                                     bq, bk, bv, nullptr, nullptr);
  attn_naive<<<dim3(SEQ / 4, NH), dim3(256), 0, stream>>>(qbuf, kbuf, vbuf, ctx);
  gemm_bt<1><<<dim3(6, 32), dim3(256), 0, stream>>>(ctx, wob, nullptr, nullptr, nullptr,
                                                    nullptr, nullptr, nullptr, bo, out);
}